// Round 5
// baseline (350.988 us; speedup 1.0000x reference)
//
#include <hip/hip_runtime.h>

// B=8, S=128, R=192, C=192. 7-point stencil on index-clamped field.
// Round-5: body identical to round-3/4 (two i-planes/thread, flat 16-load MLP,
// 107.5 us). Changes are scheduling only:
//  (a) block (48,8)=384 thr: 5 blocks x 6 waves = 30 waves/CU (94% vs 78%).
//  (b) 1D grid + swizzle: xcd = wg&7 = batch b (B=8=NXCD), and within each
//      XCD consecutive blocks sweep all 24 j-groups before advancing i-chunk.
//      Active P window/XCD ~ 14 planes ~ 2.5 MB < 4 MB L2: all i- and j-halo
//      reuse becomes XCD-local L2 hits instead of L3 round-trips.

#define BB 8
#define SS 128
#define RR 192
#define CC 192
#define PLANE (RR * CC)
#define JG   24                        // j-groups of 8 rows
#define NWG  (BB * (SS / 2) * JG)      // 12288, divisible by 8

typedef float v4f __attribute__((ext_vector_type(4)));

__device__ __forceinline__ v4f fix4(v4f c4, bool e0, bool e1)
{
    c4.x = e0 ? c4.y : c4.x;
    c4.w = e1 ? c4.z : c4.w;
    return c4;
}

__device__ __forceinline__ float stencil_pt(float pc, float pSm, float pSp,
                                            float pRm, float pRp,
                                            float pCm, float pCp, float d)
{
    const float inv2dx = 0.25f;        // 1/(2*2.0)
    const float inv2dy = 1.0f / 3.0f;  // 1/(2*1.5)
    const float inv2dz = 1.0f / 3.0f;
    const float invdx2 = 0.25f;        // 1/4.0
    const float invdy2 = 1.0f / 2.25f;
    const float invdz2 = 1.0f / 2.25f;

    float dcx = (pSp - pSm) * inv2dx;
    float dcy = (pRp - pRm) * inv2dy;
    float dcz = (pCp - pCm) * inv2dz;
    float F = dcx * dcx + dcy * dcy + dcz * dcz;
    float G = (pSp - 2.0f * pc + pSm) * invdx2
            + (pRp - 2.0f * pc + pRm) * invdy2
            + (pCp - 2.0f * pc + pCm) * invdz2;
    return -0.5f * F - d * G;
}

__global__ __launch_bounds__(384) void flowp_kernel(
    const float* __restrict__ P,
    const float* __restrict__ D,
    float* __restrict__ out)
{
    const int tx = threadIdx.x;              // 0..47
    const int k0 = tx << 2;                  // 0..188
    const bool e0 = (tx == 0);
    const bool e1 = (tx == 47);
    const int kcm = e0 ? 1 : k0 - 1;         // clamped k0-1
    const int kcp = e1 ? CC - 2 : k0 + 4;    // clamped k0+4

    // XCD-aware schedule: b = wg&7 pins batch to XCD; per XCD, j sweeps fast,
    // i-chunk advances slowly (keeps a ~2.5 MB P window resident in its L2).
    const int wg    = blockIdx.x;            // 0..12287
    const int b     = wg & 7;
    const int local = wg >> 3;               // 0..1535
    const int chunk = local / JG;            // 0..63  (slow)
    const int jg    = local - chunk * JG;    // 0..23  (fast)

    const int i0 = chunk << 1;               // 0,2,...,126
    const int i1 = i0 + 1;
    const int j  = (jg << 3) + threadIdx.y;  // 0..191

    const int cj  = min(max(j,     1), RR - 2);
    const int cjm = min(max(j - 1, 1), RR - 2);
    const int cjp = min(max(j + 1, 1), RR - 2);

    // clamped plane indices for the 4 center rows (A=i0-1, B=i0, C=i0+1, Dp=i0+2)
    const int pA = min(max(i0 - 1, 1), SS - 2);
    const int pB = max(i0, 1);               // i0 <= 126 always
    const int pC = min(i1, SS - 2);
    const int pD = min(i0 + 2, SS - 2);

    const float* Pb  = P + b * (SS * PLANE);
    const float* rA  = Pb + pA * PLANE + cj  * CC;
    const float* rB  = Pb + pB * PLANE + cj  * CC;
    const float* rC  = Pb + pC * PLANE + cj  * CC;
    const float* rDp = Pb + pD * PLANE + cj  * CC;
    const float* rm0 = Pb + pB * PLANE + cjm * CC;
    const float* rp0 = Pb + pB * PLANE + cjp * CC;
    const float* rm1 = Pb + pC * PLANE + cjm * CC;
    const float* rp1 = Pb + pC * PLANE + cjp * CC;

    const int idx0 = ((b * SS + i0) * RR + j) * CC + k0;   // unclamped
    const int idx1 = idx0 + PLANE;

    // ---- issue ALL loads up-front (16 independent memory ops) ----
    v4f vA = *(const v4f*)(rA  + k0);
    v4f vB = *(const v4f*)(rB  + k0);
    v4f vC = *(const v4f*)(rC  + k0);
    v4f vDp = *(const v4f*)(rDp + k0);
    v4f m0 = *(const v4f*)(rm0 + k0);
    v4f p0 = *(const v4f*)(rp0 + k0);
    v4f m1 = *(const v4f*)(rm1 + k0);
    v4f p1 = *(const v4f*)(rp1 + k0);
    const float Bcm = rB[kcm];
    const float Bcp = rB[kcp];
    const float Ccm = rC[kcm];
    const float Ccp = rC[kcp];
    v4f d0 = __builtin_nontemporal_load((const v4f*)(D + idx0));
    v4f d1 = __builtin_nontemporal_load((const v4f*)(D + idx1));

    // ---- k-edge fixups ----
    vA = fix4(vA, e0, e1);
    vDp = fix4(vDp, e0, e1);
    m0 = fix4(m0, e0, e1);  p0 = fix4(p0, e0, e1);
    m1 = fix4(m1, e0, e1);  p1 = fix4(p1, e0, e1);

    const float Bw1 = e0 ? vB.y : vB.x;
    const float Bw2 = vB.y;
    const float Bw3 = vB.z;
    const float Bw4 = e1 ? vB.z : vB.w;
    const float Cw1 = e0 ? vC.y : vC.x;
    const float Cw2 = vC.y;
    const float Cw3 = vC.z;
    const float Cw4 = e1 ? vC.z : vC.w;

    // ---- output at i0: Sm = A, center = B-window, Sp = C-window ----
    v4f o0;
    o0.x = stencil_pt(Bw1, vA.x, Cw1, m0.x, p0.x, Bcm, Bw2, d0.x);
    o0.y = stencil_pt(Bw2, vA.y, Cw2, m0.y, p0.y, Bw1, Bw3, d0.y);
    o0.z = stencil_pt(Bw3, vA.z, Cw3, m0.z, p0.z, Bw2, Bw4, d0.z);
    o0.w = stencil_pt(Bw4, vA.w, Cw4, m0.w, p0.w, Bw3, Bcp, d0.w);
    __builtin_nontemporal_store(o0, (v4f*)(out + idx0));

    // ---- output at i1: Sm = B-window, center = C-window, Sp = Dp ----
    v4f o1;
    o1.x = stencil_pt(Cw1, Bw1, vDp.x, m1.x, p1.x, Ccm, Cw2, d1.x);
    o1.y = stencil_pt(Cw2, Bw2, vDp.y, m1.y, p1.y, Cw1, Cw3, d1.y);
    o1.z = stencil_pt(Cw3, Bw3, vDp.z, m1.z, p1.z, Cw2, Cw4, d1.z);
    o1.w = stencil_pt(Cw4, Bw4, vDp.w, m1.w, p1.w, Cw3, Ccp, d1.w);
    __builtin_nontemporal_store(o1, (v4f*)(out + idx1));
}

extern "C" void kernel_launch(void* const* d_in, const int* in_sizes, int n_in,
                              void* d_out, int out_size, void* d_ws, size_t ws_size,
                              hipStream_t stream) {
    const float* P = (const float*)d_in[1];
    const float* D = (const float*)d_in[2];
    float* out = (float*)d_out;

    dim3 block(48, 8, 1);          // 384 threads = 6 waves; 5 blocks/CU = 94%
    dim3 grid(NWG, 1, 1);          // 12288 blocks
    flowp_kernel<<<grid, block, 0, stream>>>(P, D, out);
}

// Round 6
// 346.697 us; speedup vs baseline: 1.0124x; 1.0124x over previous
//
#include <hip/hip_runtime.h>

// B=8, S=128, R=192, C=192. 7-point stencil on index-clamped field.
// Round-6: body + block byte-identical to round-3 (two i-planes/thread, flat
// 16-load MLP, 192 thr, 107.5 us, occupancy 78%). ONLY change: 1D grid with
// XCD-aware mapping. b = wg&7 pins batch b to XCD (B=8=NXCD); within an XCD,
// j-groups sweep fast and i-chunks advance slowly, so the active P read
// window is ~4 planes ~ 590 KB << 4 MB XCD L2 -> all i-/j-halo P reuse is
// XCD-local L2 (~200cy) instead of L3/fabric (~450cy+, the round-3 wall).
// Round-5 proved the locality effect (FETCH 181->145.5 MB) but confounded it
// with an occupancy loss (384-thr blocks, 78->56%); this isolates the win.

#define BB 8
#define SS 128
#define RR 192
#define CC 192
#define PLANE (RR * CC)
#define JG   48                        // j-groups of 4 rows
#define NWG  (BB * (SS / 2) * JG)      // 24576

typedef float v4f __attribute__((ext_vector_type(4)));

__device__ __forceinline__ v4f fix4(v4f c4, bool e0, bool e1)
{
    c4.x = e0 ? c4.y : c4.x;
    c4.w = e1 ? c4.z : c4.w;
    return c4;
}

__device__ __forceinline__ float stencil_pt(float pc, float pSm, float pSp,
                                            float pRm, float pRp,
                                            float pCm, float pCp, float d)
{
    const float inv2dx = 0.25f;        // 1/(2*2.0)
    const float inv2dy = 1.0f / 3.0f;  // 1/(2*1.5)
    const float inv2dz = 1.0f / 3.0f;
    const float invdx2 = 0.25f;        // 1/4.0
    const float invdy2 = 1.0f / 2.25f;
    const float invdz2 = 1.0f / 2.25f;

    float dcx = (pSp - pSm) * inv2dx;
    float dcy = (pRp - pRm) * inv2dy;
    float dcz = (pCp - pCm) * inv2dz;
    float F = dcx * dcx + dcy * dcy + dcz * dcz;
    float G = (pSp - 2.0f * pc + pSm) * invdx2
            + (pRp - 2.0f * pc + pRm) * invdy2
            + (pCp - 2.0f * pc + pCm) * invdz2;
    return -0.5f * F - d * G;
}

// block = (48, 4): tx covers C in float4 chunks, ty covers 4 rows.
__global__ __launch_bounds__(192) void flowp_kernel(
    const float* __restrict__ P,
    const float* __restrict__ D,
    float* __restrict__ out)
{
    const int tx = threadIdx.x;              // 0..47
    const int k0 = tx << 2;                  // 0..188
    const bool e0 = (tx == 0);
    const bool e1 = (tx == 47);
    const int kcm = e0 ? 1 : k0 - 1;         // clamped k0-1
    const int kcp = e1 ? CC - 2 : k0 + 4;    // clamped k0+4

    // XCD-aware schedule: b = wg&7 pins batch to XCD; per XCD, j sweeps fast,
    // i-chunk advances slowly (active P window ~590 KB stays in its L2).
    const int wg    = blockIdx.x;            // 0..24575
    const int b     = wg & 7;
    const int local = wg >> 3;               // 0..3071
    const int chunk = local / JG;            // 0..63  (slow)
    const int jg    = local - chunk * JG;    // 0..47  (fast)

    const int i0 = chunk << 1;               // 0,2,...,126
    const int i1 = i0 + 1;
    const int j  = (jg << 2) + threadIdx.y;  // 0..191

    const int cj  = min(max(j,     1), RR - 2);
    const int cjm = min(max(j - 1, 1), RR - 2);
    const int cjp = min(max(j + 1, 1), RR - 2);

    // clamped plane indices for the 4 center rows (A=i0-1, B=i0, C=i0+1, Dp=i0+2)
    const int pA = min(max(i0 - 1, 1), SS - 2);
    const int pB = max(i0, 1);               // i0 <= 126 always
    const int pC = min(i1, SS - 2);
    const int pD = min(i0 + 2, SS - 2);

    const float* Pb  = P + b * (SS * PLANE);
    const float* rA  = Pb + pA * PLANE + cj  * CC;
    const float* rB  = Pb + pB * PLANE + cj  * CC;
    const float* rC  = Pb + pC * PLANE + cj  * CC;
    const float* rDp = Pb + pD * PLANE + cj  * CC;
    const float* rm0 = Pb + pB * PLANE + cjm * CC;
    const float* rp0 = Pb + pB * PLANE + cjp * CC;
    const float* rm1 = Pb + pC * PLANE + cjm * CC;
    const float* rp1 = Pb + pC * PLANE + cjp * CC;

    const int idx0 = ((b * SS + i0) * RR + j) * CC + k0;   // unclamped
    const int idx1 = idx0 + PLANE;

    // ---- issue ALL loads up-front (16 independent memory ops) ----
    v4f vA = *(const v4f*)(rA  + k0);
    v4f vB = *(const v4f*)(rB  + k0);
    v4f vC = *(const v4f*)(rC  + k0);
    v4f vDp = *(const v4f*)(rDp + k0);
    v4f m0 = *(const v4f*)(rm0 + k0);
    v4f p0 = *(const v4f*)(rp0 + k0);
    v4f m1 = *(const v4f*)(rm1 + k0);
    v4f p1 = *(const v4f*)(rp1 + k0);
    const float Bcm = rB[kcm];
    const float Bcp = rB[kcp];
    const float Ccm = rC[kcm];
    const float Ccp = rC[kcp];
    v4f d0 = __builtin_nontemporal_load((const v4f*)(D + idx0));
    v4f d1 = __builtin_nontemporal_load((const v4f*)(D + idx1));

    // ---- k-edge fixups ----
    vA = fix4(vA, e0, e1);
    vDp = fix4(vDp, e0, e1);
    m0 = fix4(m0, e0, e1);  p0 = fix4(p0, e0, e1);
    m1 = fix4(m1, e0, e1);  p1 = fix4(p1, e0, e1);

    const float Bw1 = e0 ? vB.y : vB.x;
    const float Bw2 = vB.y;
    const float Bw3 = vB.z;
    const float Bw4 = e1 ? vB.z : vB.w;
    const float Cw1 = e0 ? vC.y : vC.x;
    const float Cw2 = vC.y;
    const float Cw3 = vC.z;
    const float Cw4 = e1 ? vC.z : vC.w;

    // ---- output at i0: Sm = A, center = B-window, Sp = C-window ----
    v4f o0;
    o0.x = stencil_pt(Bw1, vA.x, Cw1, m0.x, p0.x, Bcm, Bw2, d0.x);
    o0.y = stencil_pt(Bw2, vA.y, Cw2, m0.y, p0.y, Bw1, Bw3, d0.y);
    o0.z = stencil_pt(Bw3, vA.z, Cw3, m0.z, p0.z, Bw2, Bw4, d0.z);
    o0.w = stencil_pt(Bw4, vA.w, Cw4, m0.w, p0.w, Bw3, Bcp, d0.w);
    __builtin_nontemporal_store(o0, (v4f*)(out + idx0));

    // ---- output at i1: Sm = B-window, center = C-window, Sp = Dp ----
    v4f o1;
    o1.x = stencil_pt(Cw1, Bw1, vDp.x, m1.x, p1.x, Ccm, Cw2, d1.x);
    o1.y = stencil_pt(Cw2, Bw2, vDp.y, m1.y, p1.y, Cw1, Cw3, d1.y);
    o1.z = stencil_pt(Cw3, Bw3, vDp.z, m1.z, p1.z, Cw2, Cw4, d1.z);
    o1.w = stencil_pt(Cw4, Bw4, vDp.w, m1.w, p1.w, Cw3, Ccp, d1.w);
    __builtin_nontemporal_store(o1, (v4f*)(out + idx1));
}

extern "C" void kernel_launch(void* const* d_in, const int* in_sizes, int n_in,
                              void* d_out, int out_size, void* d_ws, size_t ws_size,
                              hipStream_t stream) {
    const float* P = (const float*)d_in[1];
    const float* D = (const float*)d_in[2];
    float* out = (float*)d_out;

    dim3 block(48, 4, 1);          // 192 threads = 3 waves (round-3 proven)
    dim3 grid(NWG, 1, 1);          // 24576 blocks, XCD-swizzled in-kernel
    flowp_kernel<<<grid, block, 0, stream>>>(P, D, out);
}

// Round 8
// 337.990 us; speedup vs baseline: 1.0385x; 1.0258x over previous
//
#include <hip/hip_runtime.h>

// B=8, S=128, R=192, C=192. 7-point stencil on index-clamped field.
// Round-7: LDS row-staging. Grid/dispatch = round-3 (measured best: 107.5 us;
// r6 proved XCD-packing is -6 us WORSE despite -36 MB HBM -> wall is read
// SERVICE demand, not line placement). This round cuts the demand itself:
//  - 12 shared rows (6 j-rows at plane pB + 6 at pC) cooperatively staged to
//    LDS (3 v4f loads/thread); vB/m0/p0/vC/m1/p1 + 4 edge scalars read from
//    LDS. Each P line requested ONCE per block instead of ~3x.
//  - pA/pD center rows + D keep direct global loads (zero inter-thread reuse).
//  - k-edge clamp applied once at LDS-write time (compute-phase selects gone).
//  - per-block global reads 39.9 KB -> 27.6 KB; vector VMEM 16 -> 9 per thread.
// Flat schedule preserved: all loads independent, ONE barrier (not r1's chain).

#define BB 8
#define SS 128
#define RR 192
#define CC 192
#define PLANE (RR * CC)
#define PAD 200                      // LDS row stride in floats (200%32=8 banks)

typedef float v4f __attribute__((ext_vector_type(4)));

__device__ __forceinline__ v4f fix4(v4f c4, bool e0, bool e1)
{
    c4.x = e0 ? c4.y : c4.x;
    c4.w = e1 ? c4.z : c4.w;
    return c4;
}

__device__ __forceinline__ float stencil_pt(float pc, float pSm, float pSp,
                                            float pRm, float pRp,
                                            float pCm, float pCp, float d)
{
    const float inv2dx = 0.25f;        // 1/(2*2.0)
    const float inv2dy = 1.0f / 3.0f;  // 1/(2*1.5)
    const float inv2dz = 1.0f / 3.0f;
    const float invdx2 = 0.25f;        // 1/4.0
    const float invdy2 = 1.0f / 2.25f;
    const float invdz2 = 1.0f / 2.25f;

    float dcx = (pSp - pSm) * inv2dx;
    float dcy = (pRp - pRm) * inv2dy;
    float dcz = (pCp - pCm) * inv2dz;
    float F = dcx * dcx + dcy * dcy + dcz * dcz;
    float G = (pSp - 2.0f * pc + pSm) * invdx2
            + (pRp - 2.0f * pc + pRm) * invdy2
            + (pCp - 2.0f * pc + pCm) * invdz2;
    return -0.5f * F - d * G;
}

// block = (48, 4): tx covers C in float4 chunks, ty covers 4 rows.
// grid = (1, R/4, B*S/2): round-3 dispatch order (jg fastest).
__global__ __launch_bounds__(192) void flowp_kernel(
    const float* __restrict__ P,
    const float* __restrict__ D,
    float* __restrict__ out)
{
    __shared__ __align__(16) float smem[12 * PAD];   // 9600 B

    const int tx = threadIdx.x;              // 0..47
    const int ty = threadIdx.y;              // 0..3
    const int k0 = tx << 2;                  // 0..188
    const bool e0 = (tx == 0);
    const bool e1 = (tx == 47);
    const int kcm = e0 ? 1 : k0 - 1;         // clamped k0-1
    const int kcp = e1 ? CC - 2 : k0 + 4;    // clamped k0+4

    const int j0 = blockIdx.y << 2;          // 0..188
    const int j  = j0 + ty;                  // 0..191
    const int bz = blockIdx.z;               // 0..511
    const int b  = bz >> 6;
    const int i0 = (bz & 63) << 1;           // 0,2,...,126
    const int i1 = i0 + 1;

    // clamped plane indices (A=i0-1, B=i0, C=i0+1, Dp=i0+2)
    const int pA = min(max(i0 - 1, 1), SS - 2);
    const int pB = max(i0, 1);               // i0 <= 126 always
    const int pC = min(i1, SS - 2);
    const int pD = min(i0 + 2, SS - 2);

    const float* Pb = P + b * (SS * PLANE);

    // ---- staged loads: 12 rows (LDS r=0..5: plane pB rows clamp(j0-1+r);
    // r=6..11: plane pC rows clamp(j0-1+(r-6))). 3 rows per thread. ----
    v4f st0, st1, st2;
    {
        const int r0 = ty;                   // 0..3   -> pB
        const int r1 = 4 + ty;               // 4..7   -> pB(4,5) / pC(6,7)
        const int r2 = 8 + ty;               // 8..11  -> pC
        const int jr0 = min(max(j0 - 1 + r0, 1), RR - 2);
        const int jr1 = min(max(j0 - 1 + (r1 < 6 ? r1 : r1 - 6), 1), RR - 2);
        const int jr2 = min(max(j0 - 1 + (r2 - 6), 1), RR - 2);
        const int pl1 = (r1 < 6) ? pB : pC;
        st0 = *(const v4f*)(Pb + pB  * PLANE + jr0 * CC + k0);
        st1 = *(const v4f*)(Pb + pl1 * PLANE + jr1 * CC + k0);
        st2 = *(const v4f*)(Pb + pC  * PLANE + jr2 * CC + k0);
    }

    // direct loads (no inter-thread reuse): pA/pD center rows, D
    const int cj = min(max(j, 1), RR - 2);
    v4f vA  = *(const v4f*)(Pb + pA * PLANE + cj * CC + k0);
    v4f vDp = *(const v4f*)(Pb + pD * PLANE + cj * CC + k0);

    const int idx0 = ((b * SS + i0) * RR + j) * CC + k0;   // unclamped
    const int idx1 = idx0 + PLANE;
    v4f d0 = __builtin_nontemporal_load((const v4f*)(D + idx0));
    v4f d1 = __builtin_nontemporal_load((const v4f*)(D + idx1));

    // k-edge clamp applied at write time: LDS rows hold clamped values
    *(v4f*)(&smem[(ty    ) * PAD + k0]) = fix4(st0, e0, e1);
    *(v4f*)(&smem[(4 + ty) * PAD + k0]) = fix4(st1, e0, e1);
    *(v4f*)(&smem[(8 + ty) * PAD + k0]) = fix4(st2, e0, e1);
    __syncthreads();

    // ---- serve shared rows from LDS (already k-clamped) ----
    const float* rB  = &smem[(ty + 1) * PAD];   // cj   @ pB
    const float* rBm = &smem[(ty    ) * PAD];   // cjm  @ pB
    const float* rBp = &smem[(ty + 2) * PAD];   // cjp  @ pB
    const float* rC_ = &smem[(7 + ty) * PAD];   // cj   @ pC
    const float* rCm = &smem[(6 + ty) * PAD];   // cjm  @ pC
    const float* rCp = &smem[(8 + ty) * PAD];   // cjp  @ pC

    const v4f vB = *(const v4f*)(rB  + k0);
    const v4f m0 = *(const v4f*)(rBm + k0);
    const v4f p0 = *(const v4f*)(rBp + k0);
    const v4f vC = *(const v4f*)(rC_ + k0);
    const v4f m1 = *(const v4f*)(rCm + k0);
    const v4f p1 = *(const v4f*)(rCp + k0);
    const float Bcm = rB[kcm],  Bcp = rB[kcp];
    const float Ccm = rC_[kcm], Ccp = rC_[kcp];

    vA  = fix4(vA,  e0, e1);
    vDp = fix4(vDp, e0, e1);

    // ---- output at i0: Sm = vA, center = vB row, Sp = vC row ----
    v4f o0;
    o0.x = stencil_pt(vB.x, vA.x, vC.x, m0.x, p0.x, Bcm,  vB.y, d0.x);
    o0.y = stencil_pt(vB.y, vA.y, vC.y, m0.y, p0.y, vB.x, vB.z, d0.y);
    o0.z = stencil_pt(vB.z, vA.z, vC.z, m0.z, p0.z, vB.y, vB.w, d0.z);
    o0.w = stencil_pt(vB.w, vA.w, vC.w, m0.w, p0.w, vB.z, Bcp,  d0.w);
    __builtin_nontemporal_store(o0, (v4f*)(out + idx0));

    // ---- output at i1: Sm = vB row, center = vC row, Sp = vDp ----
    v4f o1;
    o1.x = stencil_pt(vC.x, vB.x, vDp.x, m1.x, p1.x, Ccm,  vC.y, d1.x);
    o1.y = stencil_pt(vC.y, vB.y, vDp.y, m1.y, p1.y, vC.x, vC.z, d1.y);
    o1.z = stencil_pt(vC.z, vB.z, vDp.z, m1.z, p1.z, vC.y, vC.w, d1.z);
    o1.w = stencil_pt(vC.w, vB.w, vDp.w, m1.w, p1.w, vC.z, Ccp,  d1.w);
    __builtin_nontemporal_store(o1, (v4f*)(out + idx1));
}

extern "C" void kernel_launch(void* const* d_in, const int* in_sizes, int n_in,
                              void* d_out, int out_size, void* d_ws, size_t ws_size,
                              hipStream_t stream) {
    const float* P = (const float*)d_in[1];
    const float* D = (const float*)d_in[2];
    float* out = (float*)d_out;

    dim3 block(48, 4, 1);                  // 192 threads = 3 waves
    dim3 grid(1, RR / 4, BB * SS / 2);     // round-3 dispatch (measured best)
    flowp_kernel<<<grid, block, 0, stream>>>(P, D, out);
}